// Round 14
// baseline (53.067 us; speedup 1.0000x reference)
//
#include <hip/hip_runtime.h>
#include <hip/hip_bf16.h>

#define M_DIM 4096
#define N_DIM 8192
#define D_DIM 256
#define C_EXP (-0.7213475204444817f) /* -1/(2 ln2): exp(-d/2) = 2^(d*C_EXP) */
#define K_ACC (1.4426950408889634f)  /* -2*C_EXP: acc coefficient */
#define SKIP_THR (-151.0f)           /* exp2f(x)==0.0f exactly for x<=-151 */

#define AS1 __attribute__((address_space(1)))
#define AS3 __attribute__((address_space(3)))

typedef __attribute__((ext_vector_type(8))) short short8; // 8 bf16 = 4 VGPR
typedef __attribute__((ext_vector_type(4))) float f32x4;  // MFMA C/D frag

__device__ inline unsigned short f2bf(float f) {
    __hip_bfloat16 h = __float2bfloat16(f);
    return *reinterpret_cast<unsigned short*>(&h);
}

// ---------------------------------------------------------------------------
// prep (unchanged from R13): fp32 -> bf16 in K-tile-blocked, swizzle-baked
// layout: plane kt = [row][slot], slot_store = slot ^ (row&7), row stride
// 128 B -> every gemm stage op is one contiguous 1 KB read.
// Also sq1[r] = ||x||^2*C_EXP; sqal[r] = {||t||^2*C_EXP, alpha[r]}.
// ---------------------------------------------------------------------------
__global__ __launch_bounds__(256) void prep_kernel(
    const float* __restrict__ X, const float* __restrict__ T,
    const float* __restrict__ alpha,
    unsigned short* __restrict__ Xb, unsigned short* __restrict__ Tb,
    float* __restrict__ sq1, float2* __restrict__ sqal)
{
    const int row  = blockIdx.x * 4 + (threadIdx.x >> 6);
    const int lane = threadIdx.x & 63;
    const float* src; char* dstB; int r, nrows; bool isX;
    if (row < M_DIM) { src = X; dstB = (char*)Xb; r = row; nrows = M_DIM; isX = true; }
    else { src = T; dstB = (char*)Tb; r = row - M_DIM; nrows = N_DIM; isX = false; }

    const float4* s4 = reinterpret_cast<const float4*>(src + (size_t)r * D_DIM);
    float4 v = s4[lane];
    float ss = v.x * v.x + v.y * v.y + v.z * v.z + v.w * v.w;

    ushort4 b4;
    b4.x = f2bf(v.x); b4.y = f2bf(v.y); b4.z = f2bf(v.z); b4.w = f2bf(v.w);
    const int gslot = lane >> 1;
    const int kt    = gslot >> 3;
    const int ss16  = (gslot & 7) ^ (r & 7);   // baked G21 involution
    *reinterpret_cast<ushort4*>(dstB +
        ((size_t)kt * nrows + r) * 128 + ss16 * 16 + (lane & 1) * 8) = b4;

    #pragma unroll
    for (int o = 1; o < 64; o <<= 1) ss += __shfl_xor(ss, o);
    if (lane == 0) {
        if (isX) sq1[r] = ss * C_EXP;
        else     sqal[r] = make_float2(ss * C_EXP, alpha[r]);
    }
}

// ---------------------------------------------------------------------------
// Fused RBF GEMM — PERSISTENT 2-job chain (R13 schedule, pipeline never
// drains mid-kernel):
//  * grid = 256 blocks (1/CU), each block runs jobs j=0,1 at (bm, bn2*2+j):
//    one continuous 8-K-tile stage chain (global K = job*4+kt); the 2-buffer
//    ping-pong ring alternates on K&1 across the job boundary. Fill/drain
//    paid once per kernel, not per tile (R7-R13 were 4-kt one-shot pipes:
//    fill+drain+lockstep-convoy ~= half the wall clock at 1 block/CU).
//  * Inter-job epilogue is BARRIER-FREE: per-wave partials go straight to
//    part2[bn*4+wc][row] (no LDS reduce, no __syncthreads -> no vmcnt(0)
//    drain of the in-flight next-job prefetch). reduce sums 128 slices.
//  * Per kt (R13): P0 stage P0u(K+1), vmcnt(8), s_barrier, read af0/bf0,
//    16 MFMA; P1/P2 same with bf1/af1; P3 register-only. Counted vmcnt
//    never drains mid-chain (tail K=7: 4/2/0). Over-retirement from the
//    epilogue's interleaved loads/stores is safe (targets are oldest ops).
//  * Race analysis unchanged: stage(K+1) targets buf (K+1)&1 whose last
//    readers (K-1) consumed their ds_reads (compiler lgkmcnt before MFMA)
//    before reaching the K P0 barrier that precedes these stage issues.
// Geometry: 256x256/job, 8 waves (2x4), wave 128x64, acc[8][4], BK=64,
// 2 x 64 KB LDS. Contiguous 1 KB stage ops (R13 layout); ds-side swizzle
// s'=s^(row&7) (0 conflicts, R11). Decode bm=t>>4, bn2=t&15: per-XCD WS
// 2.5 MB (round-robin) / 4.25 MB (chunked) -> L2-resident (L3 backstop).
// Layouts (m89/m91): A/B lane l: row/col=l&15, k=(l>>4)*8..+7 per 32-k
// window; C/D: col=lane&15, row=(lane>>4)*4+reg.
// ---------------------------------------------------------------------------
__global__ __launch_bounds__(512, 2) void gemm_kernel(
    const unsigned short* __restrict__ Xb, const unsigned short* __restrict__ Tb,
    const float* __restrict__ sq1, const float2* __restrict__ sqal,
    float* __restrict__ part2)
{
    __shared__ __align__(16) char smem[131072];
    const int t    = blockIdx.x;              // 0..255
    const int bm   = t >> 4;                  // 0..15
    const int bn2  = t & 15;                  // 0..15; job bn = bn2*2+job
    const int tid  = threadIdx.x;
    const int wid  = tid >> 6;
    const int lane = tid & 63;
    const int l15  = lane & 15, lg = lane >> 4, xr = l15 & 7;
    const int wr   = wid >> 2, wc = wid & 3;  // 2x4 waves, 128x64 out each
    const char* XbB = (const char*)Xb;
    const char* TbB = (const char*)Tb;

    // One contiguous 1 KB stage op for global K-index Kn (plane Kn&3, job
    // Kn>>2), region h (0=A rows 0-127 @0, 1=A 128-255 @32K, 2=B 0-127 @16K,
    // 3=B 128-255 @48K), 8-row block blk. Dest buffer = Kn&1.
    auto stage_op = [&](int Kn, int h, int blk) {
        const int dest = (Kn & 1) * 65536 + (h & 1) * 32768
                       + (h >> 1) * 16384 + blk * 1024;
        const char* sb = (h < 2) ? XbB : TbB;
        const int nrows = (h < 2) ? M_DIM : N_DIM;
        const int base = (h < 2) ? bm : (bn2 * 2 + (Kn >> 2));
        const int rc0 = base * 256 + (h & 1) * 128 + blk * 8;
        const size_t src = ((size_t)(Kn & 3) * nrows + rc0) * 128
                         + (size_t)lane * 16;
        __builtin_amdgcn_global_load_lds(
            (const AS1 void*)(sb + src), (AS3 void*)(smem + dest), 16, 0, 0);
    };
    auto stageP0 = [&](int Kn) {   // af0 rows + bf0 cols: 32 KB, 4 ops/wave
        if (Kn > 7) return;
        #pragma unroll
        for (int c = 0; c < 4; ++c) {
            const int o = wid * 4 + c;        // 0..31
            int h, blk;
            if (o < 16) { h = o >> 3; blk = o & 7; }
            else { const int s = o & 15; h = 2 + (s >> 3);
                   const int bb = s & 7; blk = (bb & 3) + ((bb >> 2) << 3); }
            stage_op(Kn, h, blk);
        }
    };
    auto stageP1 = [&](int Kn) {   // bf1 cols: 16 KB, 2 ops/wave
        if (Kn > 7) return;
        #pragma unroll
        for (int c = 0; c < 2; ++c) {
            const int o = wid * 2 + c;
            const int bb = o & 7;
            stage_op(Kn, 2 + (o >> 3), 4 + (bb & 3) + ((bb >> 2) << 3));
        }
    };
    auto stageP2 = [&](int Kn) {   // af1 rows: 16 KB, 2 ops/wave
        if (Kn > 7) return;
        #pragma unroll
        for (int c = 0; c < 2; ++c) {
            const int o = wid * 2 + c;
            stage_op(Kn, o >> 3, 8 + (o & 7));
        }
    };

    // prologue: stage all of K=0 (8 ops/wave in flight)
    stageP0(0); stageP1(0); stageP2(0);

    short8 af0[4][2], af1[4][2], bf0[2][2], bf1[2][2];

    #pragma unroll 1
    for (int job = 0; job < 2; ++job) {
        f32x4 acc[8][4];
        #pragma unroll
        for (int m = 0; m < 8; ++m)
            #pragma unroll
            for (int n = 0; n < 4; ++n) acc[m][n] = (f32x4)0.0f;

        #pragma unroll
        for (int kt = 0; kt < 4; ++kt) {
            const int K = job * 4 + kt;
            const char* Abase = smem + (K & 1) * 65536 + wr * 32768;
            const char* Bbase = smem + (K & 1) * 65536 + 16384
                              + (wc >> 1) * 32768 + (wc & 1) * 8192;

            // ---- P0 ----
            if (K < 7) { stageP0(K + 1);
                         asm volatile("s_waitcnt vmcnt(8)" ::: "memory"); }
            else         asm volatile("s_waitcnt vmcnt(4)" ::: "memory");
            asm volatile("s_barrier" ::: "memory");  // P0u(K) landed, all waves
            #pragma unroll
            for (int m = 0; m < 4; ++m)
                #pragma unroll
                for (int ks = 0; ks < 2; ++ks)
                    af0[m][ks] = *(const short8*)(Abase + (m * 16 + l15) * 128
                                                  + (((ks * 4 + lg) ^ xr)) * 16);
            #pragma unroll
            for (int n = 0; n < 2; ++n)
                #pragma unroll
                for (int ks = 0; ks < 2; ++ks)
                    bf0[n][ks] = *(const short8*)(Bbase + (n * 16 + l15) * 128
                                                  + (((ks * 4 + lg) ^ xr)) * 16);
            __builtin_amdgcn_s_setprio(1);
            #pragma unroll
            for (int ks = 0; ks < 2; ++ks)
                #pragma unroll
                for (int m = 0; m < 4; ++m)
                    #pragma unroll
                    for (int n = 0; n < 2; ++n)
                        acc[m][n] = __builtin_amdgcn_mfma_f32_16x16x32_bf16(
                            af0[m][ks], bf0[n][ks], acc[m][n], 0, 0, 0);
            __builtin_amdgcn_s_setprio(0);

            // ---- P1 ----
            if (K < 7) { stageP1(K + 1);
                         asm volatile("s_waitcnt vmcnt(8)" ::: "memory"); }
            else         asm volatile("s_waitcnt vmcnt(2)" ::: "memory");
            asm volatile("s_barrier" ::: "memory");
            #pragma unroll
            for (int n = 0; n < 2; ++n)
                #pragma unroll
                for (int ks = 0; ks < 2; ++ks)
                    bf1[n][ks] = *(const short8*)(Bbase + (32 + n * 16 + l15) * 128
                                                  + (((ks * 4 + lg) ^ xr)) * 16);
            __builtin_amdgcn_s_setprio(1);
            #pragma unroll
            for (int ks = 0; ks < 2; ++ks)
                #pragma unroll
                for (int m = 0; m < 4; ++m)
                    #pragma unroll
                    for (int n = 0; n < 2; ++n)
                        acc[m][2 + n] = __builtin_amdgcn_mfma_f32_16x16x32_bf16(
                            af0[m][ks], bf1[n][ks], acc[m][2 + n], 0, 0, 0);
            __builtin_amdgcn_s_setprio(0);

            // ---- P2 ----
            if (K < 7) { stageP2(K + 1);
                         asm volatile("s_waitcnt vmcnt(8)" ::: "memory"); }
            else         asm volatile("s_waitcnt vmcnt(0)" ::: "memory");
            asm volatile("s_barrier" ::: "memory");
            #pragma unroll
            for (int m = 0; m < 4; ++m)
                #pragma unroll
                for (int ks = 0; ks < 2; ++ks)
                    af1[m][ks] = *(const short8*)(Abase + (64 + m * 16 + l15) * 128
                                                  + (((ks * 4 + lg) ^ xr)) * 16);
            __builtin_amdgcn_s_setprio(1);
            #pragma unroll
            for (int ks = 0; ks < 2; ++ks)
                #pragma unroll
                for (int m = 0; m < 4; ++m)
                    #pragma unroll
                    for (int n = 0; n < 2; ++n)
                        acc[4 + m][2 + n] = __builtin_amdgcn_mfma_f32_16x16x32_bf16(
                            af1[m][ks], bf1[n][ks], acc[4 + m][2 + n], 0, 0, 0);
            __builtin_amdgcn_s_setprio(0);

            // ---- P3: register-only (af1 x bf0) ----
            __builtin_amdgcn_s_setprio(1);
            #pragma unroll
            for (int ks = 0; ks < 2; ++ks)
                #pragma unroll
                for (int m = 0; m < 4; ++m)
                    #pragma unroll
                    for (int n = 0; n < 2; ++n)
                        acc[4 + m][n] = __builtin_amdgcn_mfma_f32_16x16x32_bf16(
                            af1[m][ks], bf0[n][ks], acc[4 + m][n], 0, 0, 0);
            __builtin_amdgcn_s_setprio(0);
        }

        // ---- Barrier-free epilogue for this job (VALU + global only):
        // runs while next job's K=4/5 stages are in flight. ----
        const int bnJ = bn2 * 2 + job;
        const int rowbase = bm * 256 + wr * 128;
        float4 s1v[8];
        #pragma unroll
        for (int m = 0; m < 8; ++m)
            s1v[m] = *reinterpret_cast<const float4*>(sq1 + rowbase + m * 16 + lg * 4);
        float2 sa[4];
        #pragma unroll
        for (int n = 0; n < 4; ++n)
            sa[n] = sqal[bnJ * 256 + wc * 64 + n * 16 + l15];

        float amax = acc[0][0][0], s1m = s1v[0][0], s2m = sa[0].x;
        #pragma unroll
        for (int m = 0; m < 8; ++m)
            #pragma unroll
            for (int n = 0; n < 4; ++n)
                #pragma unroll
                for (int rr = 0; rr < 4; ++rr) amax = fmaxf(amax, acc[m][n][rr]);
        #pragma unroll
        for (int m = 0; m < 8; ++m)
            #pragma unroll
            for (int rr = 0; rr < 4; ++rr) s1m = fmaxf(s1m, s1v[m][rr]);
        #pragma unroll
        for (int n = 0; n < 4; ++n) s2m = fmaxf(s2m, sa[n].x);

        float psum[8][4];
        #pragma unroll
        for (int m = 0; m < 8; ++m)
            #pragma unroll
            for (int rr = 0; rr < 4; ++rr) psum[m][rr] = 0.0f;

        const float bound = fmaf(amax, K_ACC, s1m + s2m); // >= every arg
        if (!__all(bound < SKIP_THR)) {
            #pragma unroll
            for (int m = 0; m < 8; ++m)
                #pragma unroll
                for (int n = 0; n < 4; ++n)
                    #pragma unroll
                    for (int rr = 0; rr < 4; ++rr) {
                        const float arg = fmaf(acc[m][n][rr], K_ACC,
                                               s1v[m][rr] + sa[n].x);
                        psum[m][rr] = fmaf(__builtin_amdgcn_exp2f(arg),
                                           sa[n].y, psum[m][rr]);
                    }
        }

        // 16-lane (l15) shuffle reduce -> per-wave slice of part2 (no LDS,
        // no barrier). Slice id = bnJ*4 + wc (128 slices total).
        float* dst = part2 + ((size_t)(bnJ * 4 + wc)) * M_DIM + rowbase;
        #pragma unroll
        for (int m = 0; m < 8; ++m) {
            float4 pv;
            #pragma unroll
            for (int rr = 0; rr < 4; ++rr) {
                float p = psum[m][rr];
                p += __shfl_xor(p, 1);
                p += __shfl_xor(p, 2);
                p += __shfl_xor(p, 4);
                p += __shfl_xor(p, 8);
                ((float*)&pv)[rr] = p;
            }
            if (l15 == 0)
                *reinterpret_cast<float4*>(dst + m * 16 + lg * 4) = pv;
        }
    }
}

// ---------------------------------------------------------------------------
// reduce: out[i] = sum over 128 (bn,wc)-slices of part2[s][i]. 16 x 256.
// ---------------------------------------------------------------------------
__global__ __launch_bounds__(256) void reduce_kernel(
    const float* __restrict__ part2, float* __restrict__ out)
{
    const int gi = blockIdx.x * 256 + threadIdx.x;
    float s = 0.0f;
    #pragma unroll 8
    for (int b = 0; b < 128; ++b) s += part2[(size_t)b * M_DIM + gi];
    out[gi] = s;
}

extern "C" void kernel_launch(void* const* d_in, const int* in_sizes, int n_in,
                              void* d_out, int out_size, void* d_ws, size_t ws_size,
                              hipStream_t stream)
{
    const float* X  = (const float*)d_in[0];
    const float* T  = (const float*)d_in[1];
    const float* al = (const float*)d_in[2];
    float* out = (float*)d_out;

    char* ws = (char*)d_ws;
    unsigned short* Xb = (unsigned short*)ws;                               // 2 MiB
    unsigned short* Tb = (unsigned short*)(ws + (size_t)M_DIM * D_DIM * 2); // 4 MiB
    float* sq1  = (float*)(ws + (size_t)(M_DIM + N_DIM) * D_DIM * 2);       // 16 KiB
    float2* sqal = (float2*)(sq1 + M_DIM);                                  // 64 KiB
    float* part2 = (float*)(sqal + N_DIM);                                  // 2 MiB

    prep_kernel<<<(M_DIM + N_DIM) / 4, 256, 0, stream>>>(X, T, al, Xb, Tb, sq1, sqal);
    gemm_kernel<<<256, 512, 0, stream>>>(Xb, Tb, sq1, sqal, part2);
    reduce_kernel<<<M_DIM / 256, 256, 0, stream>>>(part2, out);
}

// Round 15
// 52.372 us; speedup vs baseline: 1.0133x; 1.0133x over previous
//
#include <hip/hip_runtime.h>
#include <hip/hip_bf16.h>

#define M_DIM 4096
#define N_DIM 8192
#define D_DIM 256
#define NSLICE 32                    /* 256-col slices of N */
#define C_EXP (-0.7213475204444817f) /* -1/(2 ln2): exp(-d/2) = 2^(d*C_EXP) */
#define K_ACC (1.4426950408889634f)  /* -2*C_EXP: acc coefficient */
#define SKIP_THR (-151.0f)           /* exp2f(x)==0.0f exactly for x<=-151 */

typedef __attribute__((ext_vector_type(8))) short short8; // 8 bf16 = 4 VGPR
typedef __attribute__((ext_vector_type(4))) float f32x4;  // MFMA C/D frag

__device__ inline unsigned short f2bf(float f) {
    __hip_bfloat16 h = __float2bfloat16(f);
    return *reinterpret_cast<unsigned short*>(&h);
}

// ---------------------------------------------------------------------------
// prep: fp32 -> bf16 rows (plain row-major); sq1[r] = ||x||^2 * C_EXP;
// sqal[r] = {||t||^2 * C_EXP, alpha[r]}. One wave per row.
// ---------------------------------------------------------------------------
__global__ __launch_bounds__(256) void prep_kernel(
    const float* __restrict__ X, const float* __restrict__ T,
    const float* __restrict__ alpha,
    unsigned short* __restrict__ Xb, unsigned short* __restrict__ Tb,
    float* __restrict__ sq1, float2* __restrict__ sqal)
{
    const int row  = blockIdx.x * 4 + (threadIdx.x >> 6);
    const int lane = threadIdx.x & 63;
    const float* src; unsigned short* dst; int r; bool isX;
    if (row < M_DIM) { src = X; dst = Xb; r = row; isX = true; }
    else             { src = T; dst = Tb; r = row - M_DIM; isX = false; }

    const float4* s4 = reinterpret_cast<const float4*>(src + (size_t)r * D_DIM);
    float4 v = s4[lane];
    float ss = v.x * v.x + v.y * v.y + v.z * v.z + v.w * v.w;

    ushort4 b4;
    b4.x = f2bf(v.x); b4.y = f2bf(v.y); b4.z = f2bf(v.z); b4.w = f2bf(v.w);
    reinterpret_cast<ushort4*>(dst + (size_t)r * D_DIM)[lane] = b4;

    #pragma unroll
    for (int o = 1; o < 64; o <<= 1) ss += __shfl_xor(ss, o);
    if (lane == 0) {
        if (isX) sq1[r] = ss * C_EXP;
        else     sqal[r] = make_float2(ss * C_EXP, alpha[r]);
    }
}

// ---------------------------------------------------------------------------
// Barrier-free fused RBF GEMM (R5 structure, register bug fixed):
//  * wave = 64 A-rows x full K=256 resident in af[4][8] (128 VGPR);
//    block = 4 waves = 256 rows x one 256-col slice; grid 512 (2 blocks/CU).
//  * B streamed L2->REGISTERS per 16-col chunk: 8 plain dwordx4 + 1 sqal
//    load, then 32 MFMA, then exp2 epilogue. NO LDS / barriers / vmcnt /
//    global_load_lds. 2048 independent waves give the MLP that streams the
//    cold working set at fill-kernel rates instead of the 0.9-1.5 TB/s the
//    barriered DMA convoy achieved (R11/R13/R14); warm re-reads run from
//    L2 at the >=24 TB/s R5 demonstrated on this exact pattern.
//  * Register budget ~226 < 256 (__launch_bounds__(256,2)): the R5 failure
//    was `#pragma unroll 2` doubling bf liveness -> af demoted to memory
//    (VGPR_Count 112, 1 GB reload storm). Here: unroll 1, single bf[8],
//    af/acc/psum all statically indexed (rule #20). Key verification
//    signal: VGPR_Count ~200-250, NOT <=128.
//  * blockIdx&31 = cslice -> XCD-pinned B slices (round-robin %8: 4 slices
//    = 2 MB B + <=2 MB A per XCD, L2-resident; L3 backstop).
// MFMA frag layouts (m89/m91): A/B lane l: row/col=l&15, k=(l>>4)*8..+7
// per 32-k window; C/D: col=lane&15, row=(lane>>4)*4+reg.
// Epilogue underflow fast-path is EXACT: exp2f(x)==0.0f for x<=-151, and
// bound >= every arg (K_ACC>0, amax/s1m/s2c are maxima).
// ---------------------------------------------------------------------------
__global__ __launch_bounds__(256, 2) void gemm_kernel(
    const unsigned short* __restrict__ Xb, const unsigned short* __restrict__ Tb,
    const float* __restrict__ sq1, const float2* __restrict__ sqal,
    float* __restrict__ part)
{
    const int cslice = blockIdx.x & 31;          // XCD-pinned B slice
    const int quad   = blockIdx.x >> 5;          // 0..15: 256-row group
    const int wid    = threadIdx.x >> 6;
    const int lane   = threadIdx.x & 63;
    const int l15    = lane & 15;
    const int lg     = lane >> 4;

    const int rowbase = quad * 256 + wid * 64;   // this wave's 64 rows
    const int colbase = cslice * 256;            // this wave's 256 cols

    // ---- A fragments: 64 rows x full K in registers (32 x dwordx4) ----
    short8 af[4][8];
    #pragma unroll
    for (int m = 0; m < 4; ++m)
        #pragma unroll
        for (int ks = 0; ks < 8; ++ks)
            af[m][ks] = *(const short8*)(Xb +
                (size_t)(rowbase + m * 16 + l15) * D_DIM + ks * 32 + lg * 8);

    // ---- sq1 for this lane's 16 (m,r) rows: row = m*16 + lg*4 + r ----
    float4 s1v[4];
    #pragma unroll
    for (int m = 0; m < 4; ++m)
        s1v[m] = *reinterpret_cast<const float4*>(sq1 + rowbase + m * 16 + lg * 4);
    float s1m = s1v[0][0];
    #pragma unroll
    for (int m = 0; m < 4; ++m)
        #pragma unroll
        for (int r = 0; r < 4; ++r) s1m = fmaxf(s1m, s1v[m][r]);

    float psum[4][4];
    #pragma unroll
    for (int m = 0; m < 4; ++m)
        #pragma unroll
        for (int r = 0; r < 4; ++r) psum[m][r] = 0.0f;

    // ---- stream B: 16 chunks of 16 cols, registers only ----
    #pragma unroll 1
    for (int c = 0; c < 16; ++c) {
        const int col = colbase + c * 16 + l15;
        const float2 sa = sqal[col];             // {sq2*C_EXP, alpha}
        short8 bf[8];
        #pragma unroll
        for (int ks = 0; ks < 8; ++ks)
            bf[ks] = *(const short8*)(Tb +
                (size_t)col * D_DIM + ks * 32 + lg * 8);

        f32x4 acc[4];
        #pragma unroll
        for (int m = 0; m < 4; ++m) acc[m] = (f32x4)0.0f;
        #pragma unroll
        for (int ks = 0; ks < 8; ++ks)
            #pragma unroll
            for (int m = 0; m < 4; ++m)
                acc[m] = __builtin_amdgcn_mfma_f32_16x16x32_bf16(
                    af[m][ks], bf[ks], acc[m], 0, 0, 0);

        // cheap monotone upper bound on all 16 args (K_ACC > 0)
        float amax = acc[0][0];
        #pragma unroll
        for (int m = 0; m < 4; ++m)
            #pragma unroll
            for (int r = 0; r < 4; ++r) amax = fmaxf(amax, acc[m][r]);
        const float bound = fmaf(amax, K_ACC, s1m + sa.x);
        if (!__all(bound < SKIP_THR)) {
            #pragma unroll
            for (int m = 0; m < 4; ++m)
                #pragma unroll
                for (int r = 0; r < 4; ++r) {
                    const float arg = fmaf(acc[m][r], K_ACC, s1v[m][r] + sa.x);
                    psum[m][r] = fmaf(__builtin_amdgcn_exp2f(arg), sa.y,
                                      psum[m][r]);
                }
        }
    }

    // ---- reduce over the 16 l15-lanes (cols) and store partials ----
    #pragma unroll
    for (int m = 0; m < 4; ++m) {
        float4 pv;
        #pragma unroll
        for (int r = 0; r < 4; ++r) {
            float p = psum[m][r];
            p += __shfl_xor(p, 1);
            p += __shfl_xor(p, 2);
            p += __shfl_xor(p, 4);
            p += __shfl_xor(p, 8);
            ((float*)&pv)[r] = p;
        }
        if (l15 == 0) // 4 lanes (lg=0..3) write 4 consecutive floats each
            *reinterpret_cast<float4*>(part + (size_t)cslice * M_DIM +
                                       rowbase + m * 16 + lg * 4) = pv;
    }
}

// ---------------------------------------------------------------------------
// reduce: out[i] = sum over 32 col-slices of part[cs][i]. 16 blocks x 256.
// ---------------------------------------------------------------------------
__global__ __launch_bounds__(256) void reduce_kernel(
    const float* __restrict__ part, float* __restrict__ out)
{
    const int gi = blockIdx.x * 256 + threadIdx.x;
    float s = 0.0f;
    #pragma unroll
    for (int b = 0; b < NSLICE; ++b) s += part[(size_t)b * M_DIM + gi];
    out[gi] = s;
}

extern "C" void kernel_launch(void* const* d_in, const int* in_sizes, int n_in,
                              void* d_out, int out_size, void* d_ws, size_t ws_size,
                              hipStream_t stream)
{
    const float* X  = (const float*)d_in[0];
    const float* T  = (const float*)d_in[1];
    const float* al = (const float*)d_in[2];
    float* out = (float*)d_out;

    char* ws = (char*)d_ws;
    unsigned short* Xb = (unsigned short*)ws;                               // 2 MiB
    unsigned short* Tb = (unsigned short*)(ws + (size_t)M_DIM * D_DIM * 2); // 4 MiB
    float* sq1  = (float*)(ws + (size_t)(M_DIM + N_DIM) * D_DIM * 2);       // 16 KiB
    float2* sqal = (float2*)(sq1 + M_DIM);                                  // 64 KiB
    float* part = (float*)(sqal + N_DIM);                                   // 512 KiB

    prep_kernel<<<(M_DIM + N_DIM) / 4, 256, 0, stream>>>(X, T, al, Xb, Tb, sq1, sqal);
    gemm_kernel<<<16 * NSLICE, 256, 0, stream>>>(Xb, Tb, sq1, sqal, part);
    reduce_kernel<<<M_DIM / 256, 256, 0, stream>>>(part, out);
}